// Round 1
// baseline (4266.858 us; speedup 1.0000x reference)
//
#include <hip/hip_runtime.h>
#include <math.h>

#define NB 8192
#define IND 512
#define QDIM 128
#define CD 1024
#define KE 8
#define PD 64

__device__ __forceinline__ float softt(float v, float th) {
    float a = fabsf(v) - th;
    return a > 0.0f ? copysignf(a, v) : 0.0f;
}

// ---------------- K0: M = Wq @ keys^T / sqrt(QDIM), sb = bq @ keys^T / sqrt(QDIM)
__global__ void k_precompute_M(const float* __restrict__ Wq, const float* __restrict__ keys,
                               const float* __restrict__ bq, float* __restrict__ M,
                               float* __restrict__ sb) {
    const float RSQ = 0.088388347648318447f; // 1/sqrt(128)
    int g = blockIdx.x * 256 + threadIdx.x;  // 0..4095
    if (g < IND * KE) {
        int i = g >> 3, k = g & 7;
        float s = 0.f;
        for (int q = 0; q < QDIM; ++q) s += Wq[i * QDIM + q] * keys[k * QDIM + q];
        M[g] = s * RSQ;  // M[i*8+k]
    }
    if (blockIdx.x == 0 && threadIdx.x < KE) {
        int k = threadIdx.x;
        float s = 0.f;
        for (int q = 0; q < QDIM; ++q) s += bq[q] * keys[k * QDIM + q];
        sb[k] = s * RSQ;
    }
}

// ---------------- K1: per-row scores -> expert idx, counts (one wave per row)
__global__ __launch_bounds__(256)
void k_scores(const float* __restrict__ x, const float* __restrict__ M,
              const float* __restrict__ sb, int* __restrict__ idx, int* __restrict__ counts) {
    __shared__ float Ms[KE][IND];
    __shared__ float sbs[KE];
    int t = threadIdx.x;
    #pragma unroll
    for (int j = 0; j < 16; ++j) {
        int e = j * 256 + t;
        Ms[e & 7][e >> 3] = M[e];
    }
    if (t < KE) sbs[t] = sb[t];
    __syncthreads();
    int w = t >> 6, lane = t & 63;
    int row = blockIdx.x * 4 + w;
    const float* xr = x + (size_t)row * IND;
    float sc[KE];
    #pragma unroll
    for (int k = 0; k < KE; ++k) sc[k] = 0.f;
    #pragma unroll
    for (int j = 0; j < IND / 64; ++j) {
        int ii = lane + 64 * j;
        float xv = xr[ii];
        #pragma unroll
        for (int k = 0; k < KE; ++k) sc[k] += xv * Ms[k][ii];
    }
    #pragma unroll
    for (int k = 0; k < KE; ++k) {
        #pragma unroll
        for (int off = 32; off >= 1; off >>= 1) sc[k] += __shfl_down(sc[k], off, 64);
    }
    if (lane == 0) {
        float smax = -1e30f;
        #pragma unroll
        for (int k = 0; k < KE; ++k) { sc[k] += sbs[k]; smax = fmaxf(smax, sc[k]); }
        const float LN09 = -0.105360515657826301f;  // ln(0.9)
        int e = 0;
        #pragma unroll
        for (int k = KE - 1; k >= 0; --k)
            if (sc[k] >= smax + LN09) e = k;  // smallest eligible k (sl is increasing)
        idx[row] = e;
        atomicAdd(&counts[e], 1);
    }
}

// ---------------- K2: exclusive prefix of counts
__global__ void k_offsets(const int* __restrict__ counts, int* __restrict__ offsets) {
    if (threadIdx.x == 0 && blockIdx.x == 0) {
        int acc = 0;
        for (int k = 0; k < KE; ++k) { offsets[k] = acc; acc += counts[k]; }
    }
}

// ---------------- K3: fill perm (compacted slot -> original row)
__global__ void k_perm(const int* __restrict__ idx, const int* __restrict__ offsets,
                       int* __restrict__ cursors, int* __restrict__ perm) {
    int r = blockIdx.x * 256 + threadIdx.x;
    if (r < NB) {
        int k = idx[r];
        int pos = atomicAdd(&cursors[k], 1);
        perm[offsets[k] + pos] = r;
    }
}

// ---------------- grouped GEMM, fp64 accumulate, 128x64 tile, 256 threads
// !ITER: Bx = gather(x) @ We[k];  BxOut <- Bx; zout <- soft(Bx)
//  ITER: zout <- soft(BxBuf + zin @ S[k])
template <int KDIM, bool ITER>
__global__ __launch_bounds__(256)
void k_gemm(const float* __restrict__ Ag, const float* __restrict__ Bg,
            const float* __restrict__ theta, const float* __restrict__ BxBuf,
            float* __restrict__ BxOut, float* __restrict__ zout,
            const int* __restrict__ perm, const int* __restrict__ counts,
            const int* __restrict__ offsets) {
    const int k = blockIdx.z;
    const int cnt = counts[k];
    const int m0 = blockIdx.y * 128;
    if (m0 >= cnt) return;
    const int n0 = blockIdx.x * 64;
    const int off = offsets[k];
    const float th = theta[k];

    __shared__ double As[16][130];  // [k][m], padded
    __shared__ double Bs[16][68];   // [k][n], padded

    const int t = threadIdx.x;
    // A staging: thread -> (row ar, k-half aq); 128 rows x 16 k
    const int ar = t >> 1;
    const int aq = t & 1;
    int mlA = m0 + ar;
    if (mlA >= cnt) mlA = m0;  // clamp to a valid row (values unused)
    const float* Arow;
    if constexpr (ITER) Arow = Ag + (size_t)(off + mlA) * CD;
    else                Arow = Ag + (size_t)perm[off + mlA] * IND;
    // B staging: thread -> (k-row br, col-quad bq4); 16 rows x 64 cols
    const int br = t >> 4;
    const int bq4 = t & 15;
    const float* Bbase = Bg + (size_t)k * KDIM * CD + (size_t)br * CD + n0 + bq4 * 4;

    const int tm = t >> 4;  // 0..15 -> rows tm*4(+64)
    const int tn = t & 15;  // 0..15 -> cols tn*4

    double acc[8][4];
    #pragma unroll
    for (int i = 0; i < 8; ++i)
        #pragma unroll
        for (int j = 0; j < 4; ++j) acc[i][j] = 0.0;

    float4 fa0, fa1, fb;
    auto gload = [&](int kt) {
        fa0 = *(const float4*)(Arow + kt * 16 + aq * 8);
        fa1 = *(const float4*)(Arow + kt * 16 + aq * 8 + 4);
        fb  = *(const float4*)(Bbase + (size_t)kt * 16 * CD);
    };
    auto sstore = [&]() {
        #pragma unroll
        for (int j = 0; j < 4; ++j) {
            As[aq * 8 + j][ar]     = (double)(&fa0.x)[j];
            As[aq * 8 + 4 + j][ar] = (double)(&fa1.x)[j];
            Bs[br][bq4 * 4 + j]    = (double)(&fb.x)[j];
        }
    };

    const int NT = KDIM / 16;
    gload(0);
    sstore();
    __syncthreads();
    for (int kt = 0; kt < NT; ++kt) {
        if (kt + 1 < NT) gload(kt + 1);
        #pragma unroll
        for (int kk = 0; kk < 16; ++kk) {
            double a[8], bb[4];
            #pragma unroll
            for (int j = 0; j < 4; ++j) {
                a[j]     = As[kk][tm * 4 + j];
                a[4 + j] = As[kk][tm * 4 + 64 + j];
                bb[j]    = Bs[kk][tn * 4 + j];
            }
            #pragma unroll
            for (int i = 0; i < 8; ++i)
                #pragma unroll
                for (int j = 0; j < 4; ++j) acc[i][j] = fma(a[i], bb[j], acc[i][j]);
        }
        __syncthreads();
        if (kt + 1 < NT) {
            sstore();
            __syncthreads();
        }
    }

    // epilogue
    #pragma unroll
    for (int i = 0; i < 8; ++i) {
        int r = tm * 4 + (i & 3) + ((i >= 4) ? 64 : 0);
        int ml = m0 + r;
        if (ml < cnt) {
            size_t addr = (size_t)(off + ml) * CD + n0 + tn * 4;
            if constexpr (!ITER) {
                float4 bx, zz;
                bx.x = (float)acc[i][0]; bx.y = (float)acc[i][1];
                bx.z = (float)acc[i][2]; bx.w = (float)acc[i][3];
                zz.x = softt(bx.x, th); zz.y = softt(bx.y, th);
                zz.z = softt(bx.z, th); zz.w = softt(bx.w, th);
                *(float4*)(BxOut + addr) = bx;
                *(float4*)(zout + addr) = zz;
            } else {
                float4 bx = *(const float4*)(BxBuf + addr);
                float4 zz;
                zz.x = softt((float)(acc[i][0] + (double)bx.x), th);
                zz.y = softt((float)(acc[i][1] + (double)bx.y), th);
                zz.z = softt((float)(acc[i][2] + (double)bx.z), th);
                zz.w = softt((float)(acc[i][3] + (double)bx.w), th);
                *(float4*)(zout + addr) = zz;
            }
        }
    }
}

// ---------------- K6: per-row top-k threshold (bitwise binary search), prune in place
__global__ __launch_bounds__(256)
void k_prune(float* __restrict__ z, const int* __restrict__ offsets) {
    __shared__ int red[4];
    const int SL[KE] = {5, 150, 296, 441, 587, 732, 878, 1024};
    int slot = blockIdx.x;
    int k = 0;
    #pragma unroll
    for (int e = 1; e < KE; ++e)
        if (slot >= offsets[e]) k = e;
    int lvl = SL[k];
    int t = threadIdx.x;
    float* zr = z + (size_t)slot * CD;
    float v[4];
    unsigned ab[4];
    #pragma unroll
    for (int j = 0; j < 4; ++j) {
        v[j] = zr[t + 256 * j];
        ab[j] = __float_as_uint(fabsf(v[j]));
    }
    unsigned thr = 0;
    for (int b = 30; b >= 0; --b) {
        unsigned cand = thr | (1u << b);
        int c = 0;
        #pragma unroll
        for (int j = 0; j < 4; ++j) c += (ab[j] >= cand) ? 1 : 0;
        #pragma unroll
        for (int off = 32; off >= 1; off >>= 1) c += __shfl_down(c, off, 64);
        if ((t & 63) == 0) red[t >> 6] = c;
        __syncthreads();
        int tot = red[0] + red[1] + red[2] + red[3];
        if (tot >= lvl) thr = cand;
        __syncthreads();
    }
    #pragma unroll
    for (int j = 0; j < 4; ++j) zr[t + 256 * j] = (ab[j] >= thr) ? v[j] : 0.f;
}

// ---------------- K7: h = relu(zhat @ W1 + b1) via sparse gather; out = h @ W2 + b2, scattered
__global__ __launch_bounds__(256)
void k_output(const float* __restrict__ z, const float* __restrict__ W1,
              const float* __restrict__ b1, const float* __restrict__ W2,
              const float* __restrict__ b2, const int* __restrict__ perm,
              float* __restrict__ out) {
    __shared__ float h[8][CD];        // 32KB
    __shared__ float wc[256 * PD];    // 64KB
    __shared__ int nnzc;
    __shared__ int nidx[CD];
    __shared__ float nval[CD];

    int t = threadIdx.x;
    int s0 = blockIdx.x * 8;
    for (int r = 0; r < 8; ++r) {
        int slot = s0 + r;
        if (t == 0) nnzc = 0;
        __syncthreads();
        const float* zr = z + (size_t)slot * CD;
        #pragma unroll
        for (int j = 0; j < 4; ++j) {
            int c = t + 256 * j;
            float v = zr[c];
            if (v != 0.f) {
                int p = atomicAdd(&nnzc, 1);
                nidx[p] = c;
                nval[p] = v;
            }
        }
        __syncthreads();
        int n = nnzc;
        for (int col = t; col < CD; col += 256) {
            float s = b1[col];
            for (int i = 0; i < n; ++i) s += nval[i] * W1[(size_t)nidx[i] * CD + col];
            h[r][col] = fmaxf(s, 0.f);
        }
        __syncthreads();
    }
    int rg = t >> 6;      // 0..3
    int col = t & 63;     // 0..63
    float o0 = 0.f, o1 = 0.f;
    for (int ch = 0; ch < 4; ++ch) {
        for (int j = 0; j < 64; ++j) {
            int e = j * 256 + t;
            wc[e] = W2[(size_t)ch * 256 * PD + e];
        }
        __syncthreads();
        for (int i = 0; i < 256; ++i) {
            float w = wc[i * PD + col];
            o0 += h[rg][ch * 256 + i] * w;
            o1 += h[rg + 4][ch * 256 + i] * w;
        }
        __syncthreads();
    }
    out[(size_t)perm[s0 + rg] * PD + col] = o0 + b2[col];
    out[(size_t)perm[s0 + rg + 4] * PD + col] = o1 + b2[col];
}

extern "C" void kernel_launch(void* const* d_in, const int* in_sizes, int n_in,
                              void* d_out, int out_size, void* d_ws, size_t ws_size,
                              hipStream_t stream) {
    const float* x     = (const float*)d_in[0];
    const float* Wq    = (const float*)d_in[1];
    const float* bq    = (const float*)d_in[2];
    const float* keys  = (const float*)d_in[3];
    const float* We    = (const float*)d_in[4];
    const float* S     = (const float*)d_in[5];
    const float* theta = (const float*)d_in[6];
    const float* W1    = (const float*)d_in[7];
    const float* b1    = (const float*)d_in[8];
    const float* W2    = (const float*)d_in[9];
    const float* b2    = (const float*)d_in[10];
    float* out = (float*)d_out;

    float* Bx = (float*)d_ws;
    float* z0 = Bx + (size_t)NB * CD;
    float* z1 = z0 + (size_t)NB * CD;
    float* M  = z1 + (size_t)NB * CD;
    float* sb = M + IND * KE;
    int* idx     = (int*)(sb + 8);
    int* perm    = idx + NB;
    int* counts  = perm + NB;   // counts[8], offsets[8], cursors[8] contiguous
    int* offsets = counts + KE;
    int* cursors = offsets + KE;

    hipMemsetAsync(counts, 0, 3 * KE * sizeof(int), stream);
    k_precompute_M<<<16, 256, 0, stream>>>(Wq, keys, bq, M, sb);
    k_scores<<<NB / 4, 256, 0, stream>>>(x, M, sb, idx, counts);
    k_offsets<<<1, 64, 0, stream>>>(counts, offsets);
    k_perm<<<NB / 256, 256, 0, stream>>>(idx, offsets, cursors, perm);

    dim3 gg(CD / 64, NB / 128, KE);
    k_gemm<IND, false><<<gg, 256, 0, stream>>>(x, We, theta, nullptr, Bx, z0, perm, counts, offsets);
    k_gemm<CD, true><<<gg, 256, 0, stream>>>(z0, S, theta, Bx, nullptr, z1, perm, counts, offsets);
    k_gemm<CD, true><<<gg, 256, 0, stream>>>(z1, S, theta, Bx, nullptr, z0, perm, counts, offsets);
    k_gemm<CD, true><<<gg, 256, 0, stream>>>(z0, S, theta, Bx, nullptr, z1, perm, counts, offsets);
    k_gemm<CD, true><<<gg, 256, 0, stream>>>(z1, S, theta, Bx, nullptr, z0, perm, counts, offsets);
    k_gemm<CD, true><<<gg, 256, 0, stream>>>(z0, S, theta, Bx, nullptr, z1, perm, counts, offsets);

    k_prune<<<NB, 256, 0, stream>>>(z1, offsets);
    k_output<<<NB / 8, 256, 0, stream>>>(z1, W1, b1, W2, b2, perm, out);
}

// Round 2
// 1907.131 us; speedup vs baseline: 2.2373x; 2.2373x over previous
//
#include <hip/hip_runtime.h>
#include <math.h>

#define NB 8192
#define IND 512
#define QDIM 128
#define CD 1024
#define KE 8
#define PD 64

__device__ __forceinline__ float softt(float v, float th) {
    float a = fabsf(v) - th;
    return a > 0.0f ? copysignf(a, v) : 0.0f;
}

// ---------------- K0: M = Wq @ keys^T / sqrt(QDIM), sb = bq @ keys^T / sqrt(QDIM)
__global__ void k_precompute_M(const float* __restrict__ Wq, const float* __restrict__ keys,
                               const float* __restrict__ bq, float* __restrict__ M,
                               float* __restrict__ sb) {
    const float RSQ = 0.088388347648318447f; // 1/sqrt(128)
    int g = blockIdx.x * 256 + threadIdx.x;  // 0..4095
    if (g < IND * KE) {
        int i = g >> 3, k = g & 7;
        float s = 0.f;
        for (int q = 0; q < QDIM; ++q) s += Wq[i * QDIM + q] * keys[k * QDIM + q];
        M[g] = s * RSQ;  // M[i*8+k]
    }
    if (blockIdx.x == 0 && threadIdx.x < KE) {
        int k = threadIdx.x;
        float s = 0.f;
        for (int q = 0; q < QDIM; ++q) s += bq[q] * keys[k * QDIM + q];
        sb[k] = s * RSQ;
    }
}

// ---------------- K1: per-row scores -> expert idx, counts (one wave per row)
__global__ __launch_bounds__(256)
void k_scores(const float* __restrict__ x, const float* __restrict__ M,
              const float* __restrict__ sb, int* __restrict__ idx, int* __restrict__ counts) {
    __shared__ float Ms[KE][IND];
    __shared__ float sbs[KE];
    int t = threadIdx.x;
    #pragma unroll
    for (int j = 0; j < 16; ++j) {
        int e = j * 256 + t;
        Ms[e & 7][e >> 3] = M[e];
    }
    if (t < KE) sbs[t] = sb[t];
    __syncthreads();
    int w = t >> 6, lane = t & 63;
    int row = blockIdx.x * 4 + w;
    const float* xr = x + (size_t)row * IND;
    float sc[KE];
    #pragma unroll
    for (int k = 0; k < KE; ++k) sc[k] = 0.f;
    #pragma unroll
    for (int j = 0; j < IND / 64; ++j) {
        int ii = lane + 64 * j;
        float xv = xr[ii];
        #pragma unroll
        for (int k = 0; k < KE; ++k) sc[k] += xv * Ms[k][ii];
    }
    #pragma unroll
    for (int k = 0; k < KE; ++k) {
        #pragma unroll
        for (int off = 32; off >= 1; off >>= 1) sc[k] += __shfl_down(sc[k], off, 64);
    }
    if (lane == 0) {
        float smax = -1e30f;
        #pragma unroll
        for (int k = 0; k < KE; ++k) { sc[k] += sbs[k]; smax = fmaxf(smax, sc[k]); }
        const float LN09 = -0.105360515657826301f;  // ln(0.9)
        int e = 0;
        #pragma unroll
        for (int k = KE - 1; k >= 0; --k)
            if (sc[k] >= smax + LN09) e = k;  // smallest eligible k (sl is increasing)
        idx[row] = e;
        atomicAdd(&counts[e], 1);
    }
}

// ---------------- K2: exclusive prefix of counts
__global__ void k_offsets(const int* __restrict__ counts, int* __restrict__ offsets) {
    if (threadIdx.x == 0 && blockIdx.x == 0) {
        int acc = 0;
        for (int k = 0; k < KE; ++k) { offsets[k] = acc; acc += counts[k]; }
    }
}

// ---------------- K3: fill perm (compacted slot -> original row)
__global__ void k_perm(const int* __restrict__ idx, const int* __restrict__ offsets,
                       int* __restrict__ cursors, int* __restrict__ perm) {
    int r = blockIdx.x * 256 + threadIdx.x;
    if (r < NB) {
        int k = idx[r];
        int pos = atomicAdd(&cursors[k], 1);
        perm[offsets[k] + pos] = r;
    }
}

// ---------------- grouped GEMM, fp32 with chunked fp32 shadow accumulation
// 128x64 tile, 256 threads, thread tile 8x4.
// Accumulate 64 k-steps (4 kt) into acc starting from zero (small magnitude,
// tiny roundings), fold into accS. Per-GEMM error ~1e-7 — rank-safe (fp64 run
// measured absmax 4.9e-4 with ~0 error; min top-k gap scale ~5e-6).
// !ITER: Bx = gather(x) @ We[k];  BxOut <- Bx; zout <- soft(Bx)
//  ITER: zout <- soft(BxBuf + zin @ S[k])
template <int KDIM, bool ITER>
__global__ __launch_bounds__(256)
void k_gemm(const float* __restrict__ Ag, const float* __restrict__ Bg,
            const float* __restrict__ theta, const float* __restrict__ BxBuf,
            float* __restrict__ BxOut, float* __restrict__ zout,
            const int* __restrict__ perm, const int* __restrict__ counts,
            const int* __restrict__ offsets) {
    const int k = blockIdx.z;
    const int cnt = counts[k];
    const int m0 = blockIdx.y * 128;
    if (m0 >= cnt) return;
    const int n0 = blockIdx.x * 64;
    const int off = offsets[k];
    const float th = theta[k];

    __shared__ float As[16][132];  // [k][m], row 528B (16B-aligned), writes 2-way (free)
    __shared__ float Bs[16][68];   // [k][n], row 272B (16B-aligned), reads 2-way (free)

    const int t = threadIdx.x;
    // A staging: thread -> (row ar, k-half aq); 128 rows x 16 k
    const int ar = t >> 1;
    const int aq = t & 1;
    int mlA = m0 + ar;
    if (mlA >= cnt) mlA = m0;  // clamp to a valid row (values unused)
    const float* Arow;
    if constexpr (ITER) Arow = Ag + (size_t)(off + mlA) * CD;
    else                Arow = Ag + (size_t)perm[off + mlA] * IND;
    // B staging: thread -> (k-row br, col-quad bq4); 16 rows x 64 cols
    const int br = t >> 4;
    const int bq4 = t & 15;
    const float* Bbase = Bg + (size_t)k * KDIM * CD + (size_t)br * CD + n0 + bq4 * 4;

    const int tm = t >> 4;  // 0..15 -> rows tm*4(+64)
    const int tn = t & 15;  // 0..15 -> cols tn*4

    float acc[8][4];   // current chunk partial (starts at 0 each chunk)
    float accS[8][4];  // chunk-sum shadow
    #pragma unroll
    for (int i = 0; i < 8; ++i)
        #pragma unroll
        for (int j = 0; j < 4; ++j) { acc[i][j] = 0.f; accS[i][j] = 0.f; }

    float4 fa0, fa1, fb;
    auto gload = [&](int kt) {
        fa0 = *(const float4*)(Arow + kt * 16 + aq * 8);
        fa1 = *(const float4*)(Arow + kt * 16 + aq * 8 + 4);
        fb  = *(const float4*)(Bbase + (size_t)kt * 16 * CD);
    };
    auto sstore = [&]() {
        #pragma unroll
        for (int j = 0; j < 4; ++j) {
            As[aq * 8 + j][ar]     = (&fa0.x)[j];
            As[aq * 8 + 4 + j][ar] = (&fa1.x)[j];
            Bs[br][bq4 * 4 + j]    = (&fb.x)[j];
        }
    };

    const int NT = KDIM / 16;
    gload(0);
    sstore();
    __syncthreads();
    for (int kt = 0; kt < NT; ++kt) {
        if (kt + 1 < NT) gload(kt + 1);
        #pragma unroll
        for (int kk = 0; kk < 16; ++kk) {
            float4 a0 = *(const float4*)&As[kk][tm * 4];
            float4 a1 = *(const float4*)&As[kk][tm * 4 + 64];
            float4 bb = *(const float4*)&Bs[kk][tn * 4];
            const float* ap0 = &a0.x;
            const float* ap1 = &a1.x;
            const float* bp = &bb.x;
            #pragma unroll
            for (int i = 0; i < 4; ++i)
                #pragma unroll
                for (int j = 0; j < 4; ++j) {
                    acc[i][j]     = fmaf(ap0[i], bp[j], acc[i][j]);
                    acc[4 + i][j] = fmaf(ap1[i], bp[j], acc[4 + i][j]);
                }
        }
        if ((kt & 3) == 3) {  // fold chunk (64 k-steps) into shadow
            #pragma unroll
            for (int i = 0; i < 8; ++i)
                #pragma unroll
                for (int j = 0; j < 4; ++j) { accS[i][j] += acc[i][j]; acc[i][j] = 0.f; }
        }
        __syncthreads();
        if (kt + 1 < NT) {
            sstore();
            __syncthreads();
        }
    }
    // NT is a multiple of 4, so acc is fully folded into accS here.

    // epilogue
    #pragma unroll
    for (int i = 0; i < 8; ++i) {
        int r = tm * 4 + (i & 3) + ((i >= 4) ? 64 : 0);
        int ml = m0 + r;
        if (ml < cnt) {
            size_t addr = (size_t)(off + ml) * CD + n0 + tn * 4;
            if constexpr (!ITER) {
                float4 bx, zz;
                bx.x = accS[i][0]; bx.y = accS[i][1];
                bx.z = accS[i][2]; bx.w = accS[i][3];
                zz.x = softt(bx.x, th); zz.y = softt(bx.y, th);
                zz.z = softt(bx.z, th); zz.w = softt(bx.w, th);
                *(float4*)(BxOut + addr) = bx;
                *(float4*)(zout + addr) = zz;
            } else {
                float4 bx = *(const float4*)(BxBuf + addr);
                float4 zz;
                zz.x = softt(accS[i][0] + bx.x, th);
                zz.y = softt(accS[i][1] + bx.y, th);
                zz.z = softt(accS[i][2] + bx.z, th);
                zz.w = softt(accS[i][3] + bx.w, th);
                *(float4*)(zout + addr) = zz;
            }
        }
    }
}

// ---------------- K6: per-row top-k threshold (bitwise binary search), prune in place
__global__ __launch_bounds__(256)
void k_prune(float* __restrict__ z, const int* __restrict__ offsets) {
    __shared__ int red[4];
    const int SL[KE] = {5, 150, 296, 441, 587, 732, 878, 1024};
    int slot = blockIdx.x;
    int k = 0;
    #pragma unroll
    for (int e = 1; e < KE; ++e)
        if (slot >= offsets[e]) k = e;
    int lvl = SL[k];
    int t = threadIdx.x;
    float* zr = z + (size_t)slot * CD;
    float v[4];
    unsigned ab[4];
    #pragma unroll
    for (int j = 0; j < 4; ++j) {
        v[j] = zr[t + 256 * j];
        ab[j] = __float_as_uint(fabsf(v[j]));
    }
    unsigned thr = 0;
    for (int b = 30; b >= 0; --b) {
        unsigned cand = thr | (1u << b);
        int c = 0;
        #pragma unroll
        for (int j = 0; j < 4; ++j) c += (ab[j] >= cand) ? 1 : 0;
        #pragma unroll
        for (int off = 32; off >= 1; off >>= 1) c += __shfl_down(c, off, 64);
        if ((t & 63) == 0) red[t >> 6] = c;
        __syncthreads();
        int tot = red[0] + red[1] + red[2] + red[3];
        if (tot >= lvl) thr = cand;
        __syncthreads();
    }
    #pragma unroll
    for (int j = 0; j < 4; ++j) zr[t + 256 * j] = (ab[j] >= thr) ? v[j] : 0.f;
}

// ---------------- K7: h = relu(zhat @ W1 + b1) via sparse gather; out = h @ W2 + b2, scattered
__global__ __launch_bounds__(256)
void k_output(const float* __restrict__ z, const float* __restrict__ W1,
              const float* __restrict__ b1, const float* __restrict__ W2,
              const float* __restrict__ b2, const int* __restrict__ perm,
              float* __restrict__ out) {
    __shared__ float h[8][CD];        // 32KB
    __shared__ float wc[256 * PD];    // 64KB
    __shared__ int nnzc;
    __shared__ int nidx[CD];
    __shared__ float nval[CD];

    int t = threadIdx.x;
    int s0 = blockIdx.x * 8;
    for (int r = 0; r < 8; ++r) {
        int slot = s0 + r;
        if (t == 0) nnzc = 0;
        __syncthreads();
        const float* zr = z + (size_t)slot * CD;
        #pragma unroll
        for (int j = 0; j < 4; ++j) {
            int c = t + 256 * j;
            float v = zr[c];
            if (v != 0.f) {
                int p = atomicAdd(&nnzc, 1);
                nidx[p] = c;
                nval[p] = v;
            }
        }
        __syncthreads();
        int n = nnzc;
        for (int col = t; col < CD; col += 256) {
            float s = b1[col];
            for (int i = 0; i < n; ++i) s += nval[i] * W1[(size_t)nidx[i] * CD + col];
            h[r][col] = fmaxf(s, 0.f);
        }
        __syncthreads();
    }
    int rg = t >> 6;      // 0..3
    int col = t & 63;     // 0..63
    float o0 = 0.f, o1 = 0.f;
    for (int ch = 0; ch < 4; ++ch) {
        for (int j = 0; j < 64; ++j) {
            int e = j * 256 + t;
            wc[e] = W2[(size_t)ch * 256 * PD + e];
        }
        __syncthreads();
        for (int i = 0; i < 256; ++i) {
            float w = wc[i * PD + col];
            o0 += h[rg][ch * 256 + i] * w;
            o1 += h[rg + 4][ch * 256 + i] * w;
        }
        __syncthreads();
    }
    out[(size_t)perm[s0 + rg] * PD + col] = o0 + b2[col];
    out[(size_t)perm[s0 + rg + 4] * PD + col] = o1 + b2[col];
}

extern "C" void kernel_launch(void* const* d_in, const int* in_sizes, int n_in,
                              void* d_out, int out_size, void* d_ws, size_t ws_size,
                              hipStream_t stream) {
    const float* x     = (const float*)d_in[0];
    const float* Wq    = (const float*)d_in[1];
    const float* bq    = (const float*)d_in[2];
    const float* keys  = (const float*)d_in[3];
    const float* We    = (const float*)d_in[4];
    const float* S     = (const float*)d_in[5];
    const float* theta = (const float*)d_in[6];
    const float* W1    = (const float*)d_in[7];
    const float* b1    = (const float*)d_in[8];
    const float* W2    = (const float*)d_in[9];
    const float* b2    = (const float*)d_in[10];
    float* out = (float*)d_out;

    float* Bx = (float*)d_ws;
    float* z0 = Bx + (size_t)NB * CD;
    float* z1 = z0 + (size_t)NB * CD;
    float* M  = z1 + (size_t)NB * CD;
    float* sb = M + IND * KE;
    int* idx     = (int*)(sb + 8);
    int* perm    = idx + NB;
    int* counts  = perm + NB;   // counts[8], offsets[8], cursors[8] contiguous
    int* offsets = counts + KE;
    int* cursors = offsets + KE;

    hipMemsetAsync(counts, 0, 3 * KE * sizeof(int), stream);
    k_precompute_M<<<16, 256, 0, stream>>>(Wq, keys, bq, M, sb);
    k_scores<<<NB / 4, 256, 0, stream>>>(x, M, sb, idx, counts);
    k_offsets<<<1, 64, 0, stream>>>(counts, offsets);
    k_perm<<<NB / 256, 256, 0, stream>>>(idx, offsets, cursors, perm);

    dim3 gg(CD / 64, NB / 128, KE);
    k_gemm<IND, false><<<gg, 256, 0, stream>>>(x, We, theta, nullptr, Bx, z0, perm, counts, offsets);
    k_gemm<CD, true><<<gg, 256, 0, stream>>>(z0, S, theta, Bx, nullptr, z1, perm, counts, offsets);
    k_gemm<CD, true><<<gg, 256, 0, stream>>>(z1, S, theta, Bx, nullptr, z0, perm, counts, offsets);
    k_gemm<CD, true><<<gg, 256, 0, stream>>>(z0, S, theta, Bx, nullptr, z1, perm, counts, offsets);
    k_gemm<CD, true><<<gg, 256, 0, stream>>>(z1, S, theta, Bx, nullptr, z0, perm, counts, offsets);
    k_gemm<CD, true><<<gg, 256, 0, stream>>>(z0, S, theta, Bx, nullptr, z1, perm, counts, offsets);

    k_prune<<<NB, 256, 0, stream>>>(z1, offsets);
    k_output<<<NB / 8, 256, 0, stream>>>(z1, W1, b1, W2, b2, perm, out);
}

// Round 3
// 1802.598 us; speedup vs baseline: 2.3671x; 1.0580x over previous
//
#include <hip/hip_runtime.h>
#include <math.h>

#define NB 8192
#define IND 512
#define QDIM 128
#define CD 1024
#define KE 8
#define PD 64
#define ORB 32  // rows per k_output block

__device__ __forceinline__ float softt(float v, float th) {
    float a = fabsf(v) - th;
    return a > 0.0f ? copysignf(a, v) : 0.0f;
}

// ---------------- K0: M = Wq @ keys^T / sqrt(QDIM), sb = bq @ keys^T / sqrt(QDIM)
__global__ void k_precompute_M(const float* __restrict__ Wq, const float* __restrict__ keys,
                               const float* __restrict__ bq, float* __restrict__ M,
                               float* __restrict__ sb) {
    const float RSQ = 0.088388347648318447f; // 1/sqrt(128)
    int g = blockIdx.x * 256 + threadIdx.x;  // 0..4095
    if (g < IND * KE) {
        int i = g >> 3, k = g & 7;
        float s = 0.f;
        for (int q = 0; q < QDIM; ++q) s += Wq[i * QDIM + q] * keys[k * QDIM + q];
        M[g] = s * RSQ;  // M[i*8+k]
    }
    if (blockIdx.x == 0 && threadIdx.x < KE) {
        int k = threadIdx.x;
        float s = 0.f;
        for (int q = 0; q < QDIM; ++q) s += bq[q] * keys[k * QDIM + q];
        sb[k] = s * RSQ;
    }
}

// ---------------- K1: per-row scores -> expert idx, counts (one wave per row)
__global__ __launch_bounds__(256)
void k_scores(const float* __restrict__ x, const float* __restrict__ M,
              const float* __restrict__ sb, int* __restrict__ idx, int* __restrict__ counts) {
    __shared__ float Ms[KE][IND];
    __shared__ float sbs[KE];
    int t = threadIdx.x;
    #pragma unroll
    for (int j = 0; j < 16; ++j) {
        int e = j * 256 + t;
        Ms[e & 7][e >> 3] = M[e];
    }
    if (t < KE) sbs[t] = sb[t];
    __syncthreads();
    int w = t >> 6, lane = t & 63;
    int row = blockIdx.x * 4 + w;
    const float* xr = x + (size_t)row * IND;
    float sc[KE];
    #pragma unroll
    for (int k = 0; k < KE; ++k) sc[k] = 0.f;
    #pragma unroll
    for (int j = 0; j < IND / 64; ++j) {
        int ii = lane + 64 * j;
        float xv = xr[ii];
        #pragma unroll
        for (int k = 0; k < KE; ++k) sc[k] += xv * Ms[k][ii];
    }
    #pragma unroll
    for (int k = 0; k < KE; ++k) {
        #pragma unroll
        for (int off = 32; off >= 1; off >>= 1) sc[k] += __shfl_down(sc[k], off, 64);
    }
    if (lane == 0) {
        float smax = -1e30f;
        #pragma unroll
        for (int k = 0; k < KE; ++k) { sc[k] += sbs[k]; smax = fmaxf(smax, sc[k]); }
        const float LN09 = -0.105360515657826301f;  // ln(0.9)
        int e = 0;
        #pragma unroll
        for (int k = KE - 1; k >= 0; --k)
            if (sc[k] >= smax + LN09) e = k;  // smallest eligible k (sl is increasing)
        idx[row] = e;
        atomicAdd(&counts[e], 1);
    }
}

// ---------------- K2: exclusive prefix of counts
__global__ void k_offsets(const int* __restrict__ counts, int* __restrict__ offsets) {
    if (threadIdx.x == 0 && blockIdx.x == 0) {
        int acc = 0;
        for (int k = 0; k < KE; ++k) { offsets[k] = acc; acc += counts[k]; }
    }
}

// ---------------- K3: fill perm (compacted slot -> original row)
__global__ void k_perm(const int* __restrict__ idx, const int* __restrict__ offsets,
                       int* __restrict__ cursors, int* __restrict__ perm) {
    int r = blockIdx.x * 256 + threadIdx.x;
    if (r < NB) {
        int k = idx[r];
        int pos = atomicAdd(&cursors[k], 1);
        perm[offsets[k] + pos] = r;
    }
}

// ---------------- grouped GEMM, fp32 with chunked fp32 shadow accumulation
template <int KDIM, bool ITER>
__global__ __launch_bounds__(256)
void k_gemm(const float* __restrict__ Ag, const float* __restrict__ Bg,
            const float* __restrict__ theta, const float* __restrict__ BxBuf,
            float* __restrict__ BxOut, float* __restrict__ zout,
            const int* __restrict__ perm, const int* __restrict__ counts,
            const int* __restrict__ offsets) {
    const int k = blockIdx.z;
    const int cnt = counts[k];
    const int m0 = blockIdx.y * 128;
    if (m0 >= cnt) return;
    const int n0 = blockIdx.x * 64;
    const int off = offsets[k];
    const float th = theta[k];

    __shared__ float As[16][132];
    __shared__ float Bs[16][68];

    const int t = threadIdx.x;
    const int ar = t >> 1;
    const int aq = t & 1;
    int mlA = m0 + ar;
    if (mlA >= cnt) mlA = m0;
    const float* Arow;
    if constexpr (ITER) Arow = Ag + (size_t)(off + mlA) * CD;
    else                Arow = Ag + (size_t)perm[off + mlA] * IND;
    const int br = t >> 4;
    const int bq4 = t & 15;
    const float* Bbase = Bg + (size_t)k * KDIM * CD + (size_t)br * CD + n0 + bq4 * 4;

    const int tm = t >> 4;
    const int tn = t & 15;

    float acc[8][4];
    float accS[8][4];
    #pragma unroll
    for (int i = 0; i < 8; ++i)
        #pragma unroll
        for (int j = 0; j < 4; ++j) { acc[i][j] = 0.f; accS[i][j] = 0.f; }

    float4 fa0, fa1, fb;
    auto gload = [&](int kt) {
        fa0 = *(const float4*)(Arow + kt * 16 + aq * 8);
        fa1 = *(const float4*)(Arow + kt * 16 + aq * 8 + 4);
        fb  = *(const float4*)(Bbase + (size_t)kt * 16 * CD);
    };
    auto sstore = [&]() {
        #pragma unroll
        for (int j = 0; j < 4; ++j) {
            As[aq * 8 + j][ar]     = (&fa0.x)[j];
            As[aq * 8 + 4 + j][ar] = (&fa1.x)[j];
            Bs[br][bq4 * 4 + j]    = (&fb.x)[j];
        }
    };

    const int NT = KDIM / 16;
    gload(0);
    sstore();
    __syncthreads();
    for (int kt = 0; kt < NT; ++kt) {
        if (kt + 1 < NT) gload(kt + 1);
        #pragma unroll
        for (int kk = 0; kk < 16; ++kk) {
            float4 a0 = *(const float4*)&As[kk][tm * 4];
            float4 a1 = *(const float4*)&As[kk][tm * 4 + 64];
            float4 bb = *(const float4*)&Bs[kk][tn * 4];
            const float* ap0 = &a0.x;
            const float* ap1 = &a1.x;
            const float* bp = &bb.x;
            #pragma unroll
            for (int i = 0; i < 4; ++i)
                #pragma unroll
                for (int j = 0; j < 4; ++j) {
                    acc[i][j]     = fmaf(ap0[i], bp[j], acc[i][j]);
                    acc[4 + i][j] = fmaf(ap1[i], bp[j], acc[4 + i][j]);
                }
        }
        if ((kt & 3) == 3) {
            #pragma unroll
            for (int i = 0; i < 8; ++i)
                #pragma unroll
                for (int j = 0; j < 4; ++j) { accS[i][j] += acc[i][j]; acc[i][j] = 0.f; }
        }
        __syncthreads();
        if (kt + 1 < NT) {
            sstore();
            __syncthreads();
        }
    }

    #pragma unroll
    for (int i = 0; i < 8; ++i) {
        int r = tm * 4 + (i & 3) + ((i >= 4) ? 64 : 0);
        int ml = m0 + r;
        if (ml < cnt) {
            size_t addr = (size_t)(off + ml) * CD + n0 + tn * 4;
            if constexpr (!ITER) {
                float4 bx, zz;
                bx.x = accS[i][0]; bx.y = accS[i][1];
                bx.z = accS[i][2]; bx.w = accS[i][3];
                zz.x = softt(bx.x, th); zz.y = softt(bx.y, th);
                zz.z = softt(bx.z, th); zz.w = softt(bx.w, th);
                *(float4*)(BxOut + addr) = bx;
                *(float4*)(zout + addr) = zz;
            } else {
                float4 bx = *(const float4*)(BxBuf + addr);
                float4 zz;
                zz.x = softt(accS[i][0] + bx.x, th);
                zz.y = softt(accS[i][1] + bx.y, th);
                zz.z = softt(accS[i][2] + bx.z, th);
                zz.w = softt(accS[i][3] + bx.w, th);
                *(float4*)(zout + addr) = zz;
            }
        }
    }
}

// ---------------- K6: per-row top-k threshold (bit search), emit compact (val,idx) lists
// thr converges to the exact bits of the kth-largest |z|; keeping ab >= thr
// reproduces reference `az >= kth` semantics (incl. ties / kth==0 cases).
__global__ __launch_bounds__(256)
void k_prune(const float* __restrict__ z, const int* __restrict__ offsets,
             float* __restrict__ cval, int* __restrict__ cidx, int* __restrict__ rcnt) {
    __shared__ int red[4];
    __shared__ int wcnt;
    const int SL[KE] = {5, 150, 296, 441, 587, 732, 878, 1024};
    int slot = blockIdx.x;
    int k = 0;
    #pragma unroll
    for (int e = 1; e < KE; ++e)
        if (slot >= offsets[e]) k = e;
    int lvl = SL[k];
    int t = threadIdx.x;
    if (t == 0) wcnt = 0;
    const float* zr = z + (size_t)slot * CD;
    float v[4];
    unsigned ab[4];
    #pragma unroll
    for (int j = 0; j < 4; ++j) {
        v[j] = zr[t + 256 * j];
        ab[j] = __float_as_uint(fabsf(v[j]));
    }
    unsigned thr = 0;
    for (int b = 30; b >= 0; --b) {
        unsigned cand = thr | (1u << b);
        int c = 0;
        #pragma unroll
        for (int j = 0; j < 4; ++j) c += (ab[j] >= cand) ? 1 : 0;
        #pragma unroll
        for (int off = 32; off >= 1; off >>= 1) c += __shfl_down(c, off, 64);
        if ((t & 63) == 0) red[t >> 6] = c;
        __syncthreads();
        int tot = red[0] + red[1] + red[2] + red[3];
        if (tot >= lvl) thr = cand;
        __syncthreads();
    }
    float* cvr = cval + (size_t)slot * CD;
    int* cir = cidx + (size_t)slot * CD;
    #pragma unroll
    for (int j = 0; j < 4; ++j) {
        if (ab[j] >= thr) {
            int p = atomicAdd(&wcnt, 1);
            cvr[p] = v[j];
            cir[p] = t + 256 * j;
        }
    }
    __syncthreads();
    if (t == 0) rcnt[slot] = wcnt;
}

// ---------------- K7: out = relu(h) @ W2 + b2, h = b1 + sparse_z @ W1 (compact lists)
// 256 blocks x 32 rows; K-chunks of 64; thread tile 2 rows x 4 cols.
__global__ __launch_bounds__(256)
void k_output(const float* __restrict__ cval, const int* __restrict__ cidx,
              const int* __restrict__ rcnt,
              const float* __restrict__ W1, const float* __restrict__ b1,
              const float* __restrict__ W2, const float* __restrict__ b2,
              const int* __restrict__ perm, float* __restrict__ out) {
    __shared__ float W2s[64][68];   // [k][n] chunk, pad 68
    __shared__ float hTs[64][34];   // [k][r], pad 34 (even -> float2 aligned)
    __shared__ float cvS[ORB][16];
    __shared__ int   ciS[ORB][16];
    __shared__ int   cnS[ORB];

    const int t = threadIdx.x;
    const int s0 = blockIdx.x * ORB;

    if (t < ORB) cnS[t] = rcnt[s0 + t];
    __syncthreads();
    // stage capped (<=16) lists; zero-fill beyond cnt so h-phase FMAs are unconditional
    #pragma unroll
    for (int u = t; u < ORB * 16; u += 256) {
        int r = u >> 4, e = u & 15;
        int cnt = cnS[r];
        cvS[r][e] = (e < cnt) ? cval[(size_t)(s0 + r) * CD + e] : 0.f;
        ciS[r][e] = (e < cnt) ? cidx[(size_t)(s0 + r) * CD + e] : 0;
    }

    const int tm = t >> 4;   // 0..15 -> rows 2tm, 2tm+1
    const int tn = t & 15;   // 0..15 -> cols 4tn
    const int iL = t & 63;   // h-phase: i within chunk
    const int rs = t >> 6;   // h-phase: wave id -> rows rs*8..rs*8+7

    float acc0[4], acc1[4];
    #pragma unroll
    for (int j = 0; j < 4; ++j) { acc0[j] = 0.f; acc1[j] = 0.f; }

    for (int ch = 0; ch < 16; ++ch) {
        const int i0 = ch * 64;
        __syncthreads();  // protect previous chunk's LDS reads
        // stage W2 chunk: 64x64, each thread 4 float4s
        #pragma unroll
        for (int p = 0; p < 4; ++p) {
            int kr = (t >> 4) + 16 * p;
            float4 w = *(const float4*)&W2[(size_t)(i0 + kr) * PD + (t & 15) * 4];
            *(float4*)&W2s[kr][(t & 15) * 4] = w;
        }
        // compute hT chunk: one wave per row (uniform cnt), 8 rows per wave
        float bv = b1[i0 + iL];
        #pragma unroll
        for (int jj = 0; jj < 8; ++jj) {
            int r = rs * 8 + jj;
            int cnt = cnS[r];
            float acc = bv;
            float wv[16];
            #pragma unroll
            for (int e = 0; e < 16; ++e)
                wv[e] = W1[(size_t)ciS[r][e] * CD + i0 + iL];
            #pragma unroll
            for (int e = 0; e < 16; ++e)
                acc = fmaf(cvS[r][e], wv[e], acc);
            if (cnt > 16) {  // rare fallback: stream remainder from global
                const float* cvr = cval + (size_t)(s0 + r) * CD;
                const int* cir = cidx + (size_t)(s0 + r) * CD;
                for (int e = 16; e < cnt; ++e)
                    acc = fmaf(cvr[e], W1[(size_t)cir[e] * CD + i0 + iL], acc);
            }
            hTs[iL][r] = fmaxf(acc, 0.f);
        }
        __syncthreads();
        // GEMM accumulate over this chunk
        #pragma unroll 8
        for (int i = 0; i < 64; ++i) {
            float2 h2 = *(const float2*)&hTs[i][2 * tm];
            float4 w4 = *(const float4*)&W2s[i][4 * tn];
            const float* wp = &w4.x;
            #pragma unroll
            for (int j = 0; j < 4; ++j) {
                acc0[j] = fmaf(h2.x, wp[j], acc0[j]);
                acc1[j] = fmaf(h2.y, wp[j], acc1[j]);
            }
        }
    }

    float4 bb = *(const float4*)&b2[4 * tn];
    const float* bp = &bb.x;
    int g0 = perm[s0 + 2 * tm];
    int g1 = perm[s0 + 2 * tm + 1];
    float4 o0, o1;
    #pragma unroll
    for (int j = 0; j < 4; ++j) { (&o0.x)[j] = acc0[j] + bp[j]; (&o1.x)[j] = acc1[j] + bp[j]; }
    *(float4*)&out[(size_t)g0 * PD + 4 * tn] = o0;
    *(float4*)&out[(size_t)g1 * PD + 4 * tn] = o1;
}

extern "C" void kernel_launch(void* const* d_in, const int* in_sizes, int n_in,
                              void* d_out, int out_size, void* d_ws, size_t ws_size,
                              hipStream_t stream) {
    const float* x     = (const float*)d_in[0];
    const float* Wq    = (const float*)d_in[1];
    const float* bq    = (const float*)d_in[2];
    const float* keys  = (const float*)d_in[3];
    const float* We    = (const float*)d_in[4];
    const float* S     = (const float*)d_in[5];
    const float* theta = (const float*)d_in[6];
    const float* W1    = (const float*)d_in[7];
    const float* b1    = (const float*)d_in[8];
    const float* W2    = (const float*)d_in[9];
    const float* b2    = (const float*)d_in[10];
    float* out = (float*)d_out;

    float* Bx = (float*)d_ws;
    float* z0 = Bx + (size_t)NB * CD;
    float* z1 = z0 + (size_t)NB * CD;
    float* M  = z1 + (size_t)NB * CD;
    float* sb = M + IND * KE;
    int* idx     = (int*)(sb + 8);
    int* perm    = idx + NB;
    int* counts  = perm + NB;
    int* offsets = counts + KE;
    int* cursors = offsets + KE;
    int* rcnt    = cursors + KE;
    // compact lists alias Bx / z0 (dead after the last k_gemm, stream-ordered)
    float* cval = Bx;
    int*   cidx = (int*)z0;

    hipMemsetAsync(counts, 0, 3 * KE * sizeof(int), stream);
    k_precompute_M<<<16, 256, 0, stream>>>(Wq, keys, bq, M, sb);
    k_scores<<<NB / 4, 256, 0, stream>>>(x, M, sb, idx, counts);
    k_offsets<<<1, 64, 0, stream>>>(counts, offsets);
    k_perm<<<NB / 256, 256, 0, stream>>>(idx, offsets, cursors, perm);

    dim3 gg(CD / 64, NB / 128, KE);
    k_gemm<IND, false><<<gg, 256, 0, stream>>>(x, We, theta, nullptr, Bx, z0, perm, counts, offsets);
    k_gemm<CD, true><<<gg, 256, 0, stream>>>(z0, S, theta, Bx, nullptr, z1, perm, counts, offsets);
    k_gemm<CD, true><<<gg, 256, 0, stream>>>(z1, S, theta, Bx, nullptr, z0, perm, counts, offsets);
    k_gemm<CD, true><<<gg, 256, 0, stream>>>(z0, S, theta, Bx, nullptr, z1, perm, counts, offsets);
    k_gemm<CD, true><<<gg, 256, 0, stream>>>(z1, S, theta, Bx, nullptr, z0, perm, counts, offsets);
    k_gemm<CD, true><<<gg, 256, 0, stream>>>(z0, S, theta, Bx, nullptr, z1, perm, counts, offsets);

    k_prune<<<NB, 256, 0, stream>>>(z1, offsets, cval, cidx, rcnt);
    k_output<<<NB / ORB, 256, 0, stream>>>(cval, cidx, rcnt, W1, b1, W2, b2, perm, out);
}

// Round 4
// 1213.650 us; speedup vs baseline: 3.5157x; 1.4853x over previous
//
#include <hip/hip_runtime.h>
#include <math.h>

#define NB 8192
#define IND 512
#define QDIM 128
#define CD 1024
#define KE 8
#define PD 64
#define ORB 32  // rows per k_output block

typedef _Float16 h8 __attribute__((ext_vector_type(8)));
typedef _Float16 h4 __attribute__((ext_vector_type(4)));
typedef float fx16 __attribute__((ext_vector_type(16)));

#define GLD16(g, l) __builtin_amdgcn_global_load_lds((const __attribute__((address_space(1))) void*)(g), (__attribute__((address_space(3))) void*)(l), 16, 0, 0)

__device__ __forceinline__ float softt(float v, float th) {
    float a = fabsf(v) - th;
    return a > 0.0f ? copysignf(a, v) : 0.0f;
}

// ---------------- split helpers: v = hi + lo * 2^-11 (lo stored pre-scaled by 2048)
__device__ __forceinline__ void fsplit(float v, _Float16& hi, _Float16& lo) {
    hi = (_Float16)v;
    lo = (_Float16)((v - (float)hi) * 2048.0f);
}

// ---------------- K0: M = Wq @ keys^T / sqrt(QDIM), sb = bq @ keys^T / sqrt(QDIM)
__global__ void k_precompute_M(const float* __restrict__ Wq, const float* __restrict__ keys,
                               const float* __restrict__ bq, float* __restrict__ M,
                               float* __restrict__ sb) {
    const float RSQ = 0.088388347648318447f; // 1/sqrt(128)
    int g = blockIdx.x * 256 + threadIdx.x;  // 0..4095
    if (g < IND * KE) {
        int i = g >> 3, k = g & 7;
        float s = 0.f;
        for (int q = 0; q < QDIM; ++q) s += Wq[i * QDIM + q] * keys[k * QDIM + q];
        M[g] = s * RSQ;  // M[i*8+k]
    }
    if (blockIdx.x == 0 && threadIdx.x < KE) {
        int k = threadIdx.x;
        float s = 0.f;
        for (int q = 0; q < QDIM; ++q) s += bq[q] * keys[k * QDIM + q];
        sb[k] = s * RSQ;
    }
}

// ---------------- K1: per-row scores -> expert idx, counts (one wave per row)
__global__ __launch_bounds__(256)
void k_scores(const float* __restrict__ x, const float* __restrict__ M,
              const float* __restrict__ sb, int* __restrict__ idx, int* __restrict__ counts) {
    __shared__ float Ms[KE][IND];
    __shared__ float sbs[KE];
    int t = threadIdx.x;
    #pragma unroll
    for (int j = 0; j < 16; ++j) {
        int e = j * 256 + t;
        Ms[e & 7][e >> 3] = M[e];
    }
    if (t < KE) sbs[t] = sb[t];
    __syncthreads();
    int w = t >> 6, lane = t & 63;
    int row = blockIdx.x * 4 + w;
    const float* xr = x + (size_t)row * IND;
    float sc[KE];
    #pragma unroll
    for (int k = 0; k < KE; ++k) sc[k] = 0.f;
    #pragma unroll
    for (int j = 0; j < IND / 64; ++j) {
        int ii = lane + 64 * j;
        float xv = xr[ii];
        #pragma unroll
        for (int k = 0; k < KE; ++k) sc[k] += xv * Ms[k][ii];
    }
    #pragma unroll
    for (int k = 0; k < KE; ++k) {
        #pragma unroll
        for (int off = 32; off >= 1; off >>= 1) sc[k] += __shfl_down(sc[k], off, 64);
    }
    if (lane == 0) {
        float smax = -1e30f;
        #pragma unroll
        for (int k = 0; k < KE; ++k) { sc[k] += sbs[k]; smax = fmaxf(smax, sc[k]); }
        const float LN09 = -0.105360515657826301f;  // ln(0.9)
        int e = 0;
        #pragma unroll
        for (int k = KE - 1; k >= 0; --k)
            if (sc[k] >= smax + LN09) e = k;  // smallest eligible k (sl is increasing)
        idx[row] = e;
        atomicAdd(&counts[e], 1);
    }
}

// ---------------- K2: exclusive prefix of counts
__global__ void k_offsets(const int* __restrict__ counts, int* __restrict__ offsets) {
    if (threadIdx.x == 0 && blockIdx.x == 0) {
        int acc = 0;
        for (int k = 0; k < KE; ++k) { offsets[k] = acc; acc += counts[k]; }
    }
}

// ---------------- K3: fill perm (compacted slot -> original row)
__global__ void k_perm(const int* __restrict__ idx, const int* __restrict__ offsets,
                       int* __restrict__ cursors, int* __restrict__ perm) {
    int r = blockIdx.x * 256 + threadIdx.x;
    if (r < NB) {
        int k = idx[r];
        int pos = atomicAdd(&cursors[k], 1);
        perm[offsets[k] + pos] = r;
    }
}

// ---------------- K4: elementwise split of x into hi/lo fp16 planes
__global__ __launch_bounds__(256)
void k_split_rows(const float* __restrict__ src, _Float16* __restrict__ ph,
                  _Float16* __restrict__ pl, int n) {
    int i = (blockIdx.x * 256 + threadIdx.x) * 4;
    if (i < n) {
        float4 v = *(const float4*)(src + i);
        h4 hh, ll;
        #pragma unroll
        for (int j = 0; j < 4; ++j) {
            _Float16 a, b;
            fsplit((&v.x)[j], a, b);
            hh[j] = a; ll[j] = b;
        }
        *(h4*)(ph + i) = hh;
        *(h4*)(pl + i) = ll;
    }
}

// ---------------- K5: transpose+split: src[e][K][CD] fp32 -> th/tl[e][CD][K] fp16
__global__ __launch_bounds__(256)
void k_tsplit(const float* __restrict__ src, _Float16* __restrict__ th,
              _Float16* __restrict__ tl, int K) {
    __shared__ float tile[64][65];
    int e = blockIdx.z;
    int k0 = blockIdx.x * 64;
    int n0 = blockIdx.y * 64;
    const float* s = src + (size_t)e * K * CD;
    int t = threadIdx.x;
    int tr = t >> 4;
    int tc = (t & 15) * 4;
    #pragma unroll
    for (int p = 0; p < 4; ++p) {
        int kk = tr + p * 16;
        float4 v = *(const float4*)&s[(size_t)(k0 + kk) * CD + n0 + tc];
        #pragma unroll
        for (int j = 0; j < 4; ++j) tile[kk][tc + j] = (&v.x)[j];
    }
    __syncthreads();
    int n = t >> 2;
    int kq = (t & 3) * 16;
    h8 hh0, hh1, ll0, ll1;
    #pragma unroll
    for (int j = 0; j < 8; ++j) {
        _Float16 a, b;
        fsplit(tile[kq + j][n], a, b);
        hh0[j] = a; ll0[j] = b;
        fsplit(tile[kq + 8 + j][n], a, b);
        hh1[j] = a; ll1[j] = b;
    }
    size_t ob = ((size_t)e * CD + n0 + n) * K + k0 + kq;
    *(h8*)(th + ob) = hh0;
    *(h8*)(th + ob + 8) = hh1;
    *(h8*)(tl + ob) = ll0;
    *(h8*)(tl + ob + 8) = ll1;
}

// ---------------- grouped split-fp16 MFMA GEMM
// A planes: [row][KDIM] fp16 hi/lo (lo pre-scaled 2048). B planes: [e][CD][KDIM] K-major.
// LDS row layout: 128 rows x 8 chunks of 16B; physical chunk = logical ^ (row&7).
// logical chunk lc = kg*2 + comp, kg = (k_halves)>>3.
// MODE 0: first GEMM (A rows via perm): write Bx fp32 + z hi/lo
// MODE 1: iter: v += Bx; write z hi/lo
// MODE 2: last iter: v += Bx; write z fp32
template <int KDIM, int MODE>
__global__ __launch_bounds__(256)
void k_mfma(const _Float16* __restrict__ Ah, const _Float16* __restrict__ Al,
            const _Float16* __restrict__ Bh, const _Float16* __restrict__ Bl,
            const float* __restrict__ theta, const float* __restrict__ BxBuf,
            float* __restrict__ BxOut, _Float16* __restrict__ zh, _Float16* __restrict__ zl,
            float* __restrict__ zf,
            const int* __restrict__ perm, const int* __restrict__ counts,
            const int* __restrict__ offsets) {
    const int e = blockIdx.z;
    const int cnt = counts[e];
    const int m0 = blockIdx.y * 128;
    if (m0 >= cnt) return;
    const int n0 = blockIdx.x * 128;
    const int off = offsets[e];
    const float th = theta[e];

    __shared__ _Float16 Asl[128 * 64];  // 16 KB
    __shared__ _Float16 Bsl[128 * 64];  // 16 KB

    const int t = threadIdx.x;
    const int lane = t & 63;
    const int w = t >> 6;

    // staging pointers: 4 A + 4 B global_load_lds per thread per BK=32 step
    const _Float16* aptr[4];
    const _Float16* bptr[4];
    _Float16* alds[4];
    _Float16* blds[4];
    #pragma unroll
    for (int i = 0; i < 4; ++i) {
        int s = w * 4 + i;
        int r = s * 8 + (lane >> 3);
        int pc = lane & 7;
        int lc = pc ^ (r & 7);
        int comp = lc & 1;
        int kg = lc >> 1;
        int mrow = m0 + r; if (mrow > cnt - 1) mrow = cnt - 1;
        size_t grow;
        if constexpr (MODE == 0) grow = (size_t)perm[off + mrow];
        else grow = (size_t)(off + mrow);
        aptr[i] = (comp ? Al : Ah) + grow * KDIM + kg * 8;
        bptr[i] = (comp ? Bl : Bh) + ((size_t)e * CD + n0 + r) * KDIM + kg * 8;
        alds[i] = Asl + s * 512;
        blds[i] = Bsl + s * 512;
    }

    const int wm = w >> 1, wn = w & 1;
    const int q = lane >> 5;
    const int ml = lane & 31;
    const int sw = ml & 7;

    fx16 acc1[2][2], acc2[2][2];
    #pragma unroll
    for (int mt = 0; mt < 2; ++mt)
        #pragma unroll
        for (int nt = 0; nt < 2; ++nt)
            #pragma unroll
            for (int g = 0; g < 16; ++g) { acc1[mt][nt][g] = 0.f; acc2[mt][nt][g] = 0.f; }

    const int NT = KDIM / 32;
    for (int kt = 0; kt < NT; ++kt) {
        const int k0h = kt * 32;
        #pragma unroll
        for (int i = 0; i < 4; ++i) {
            GLD16(aptr[i] + k0h, alds[i]);
            GLD16(bptr[i] + k0h, blds[i]);
        }
        __syncthreads();
        #pragma unroll
        for (int ks = 0; ks < 2; ++ks) {
            const int base = ks * 4 + q * 2;
            h8 ah[2], al2[2], bh2[2], bl2[2];
            #pragma unroll
            for (int mt = 0; mt < 2; ++mt) {
                int mb = (wm * 64 + mt * 32 + ml) * 64;
                ah[mt]  = *(const h8*)&Asl[mb + (((base + 0) ^ sw) * 8)];
                al2[mt] = *(const h8*)&Asl[mb + (((base + 1) ^ sw) * 8)];
            }
            #pragma unroll
            for (int nt = 0; nt < 2; ++nt) {
                int nb = (wn * 64 + nt * 32 + ml) * 64;
                bh2[nt] = *(const h8*)&Bsl[nb + (((base + 0) ^ sw) * 8)];
                bl2[nt] = *(const h8*)&Bsl[nb + (((base + 1) ^ sw) * 8)];
            }
            #pragma unroll
            for (int mt = 0; mt < 2; ++mt)
                #pragma unroll
                for (int nt = 0; nt < 2; ++nt) {
                    acc1[mt][nt] = __builtin_amdgcn_mfma_f32_32x32x16_f16(ah[mt],  bh2[nt], acc1[mt][nt], 0, 0, 0);
                    acc2[mt][nt] = __builtin_amdgcn_mfma_f32_32x32x16_f16(ah[mt],  bl2[nt], acc2[mt][nt], 0, 0, 0);
                    acc2[mt][nt] = __builtin_amdgcn_mfma_f32_32x32x16_f16(al2[mt], bh2[nt], acc2[mt][nt], 0, 0, 0);
                }
        }
        __syncthreads();
    }

    // epilogue: C/D layout col=lane&31, row=(g&3)+8*(g>>2)+4*q  [m74/m101]
    const float LSC = 4.8828125e-4f;  // 2^-11
    #pragma unroll
    for (int mt = 0; mt < 2; ++mt)
        #pragma unroll
        for (int nt = 0; nt < 2; ++nt) {
            #pragma unroll
            for (int g = 0; g < 16; ++g) {
                int rl = wm * 64 + mt * 32 + (g & 3) + 8 * (g >> 2) + 4 * q;
                int mrow = m0 + rl;
                if (mrow < cnt) {
                    int col = n0 + wn * 64 + nt * 32 + ml;
                    size_t addr = (size_t)(off + mrow) * CD + col;
                    float v = acc1[mt][nt][g] + acc2[mt][nt][g] * LSC;
                    if constexpr (MODE == 0) {
                        BxOut[addr] = v;
                        float z = softt(v, th);
                        _Float16 a, b;
                        fsplit(z, a, b);
                        zh[addr] = a; zl[addr] = b;
                    } else if constexpr (MODE == 1) {
                        float z = softt(v + BxBuf[addr], th);
                        _Float16 a, b;
                        fsplit(z, a, b);
                        zh[addr] = a; zl[addr] = b;
                    } else {
                        zf[addr] = softt(v + BxBuf[addr], th);
                    }
                }
            }
        }
}

// ---------------- K6: per-row top-k threshold (bit search), emit compact (val,idx) lists
__global__ __launch_bounds__(256)
void k_prune(const float* __restrict__ z, const int* __restrict__ offsets,
             float* __restrict__ cval, int* __restrict__ cidx, int* __restrict__ rcnt) {
    __shared__ int red[4];
    __shared__ int wcnt;
    const int SL[KE] = {5, 150, 296, 441, 587, 732, 878, 1024};
    int slot = blockIdx.x;
    int k = 0;
    #pragma unroll
    for (int e = 1; e < KE; ++e)
        if (slot >= offsets[e]) k = e;
    int lvl = SL[k];
    int t = threadIdx.x;
    if (t == 0) wcnt = 0;
    const float* zr = z + (size_t)slot * CD;
    float v[4];
    unsigned ab[4];
    #pragma unroll
    for (int j = 0; j < 4; ++j) {
        v[j] = zr[t + 256 * j];
        ab[j] = __float_as_uint(fabsf(v[j]));
    }
    unsigned thr = 0;
    for (int b = 30; b >= 0; --b) {
        unsigned cand = thr | (1u << b);
        int c = 0;
        #pragma unroll
        for (int j = 0; j < 4; ++j) c += (ab[j] >= cand) ? 1 : 0;
        #pragma unroll
        for (int off = 32; off >= 1; off >>= 1) c += __shfl_down(c, off, 64);
        if ((t & 63) == 0) red[t >> 6] = c;
        __syncthreads();
        int tot = red[0] + red[1] + red[2] + red[3];
        if (tot >= lvl) thr = cand;
        __syncthreads();
    }
    float* cvr = cval + (size_t)slot * CD;
    int* cir = cidx + (size_t)slot * CD;
    #pragma unroll
    for (int j = 0; j < 4; ++j) {
        if (ab[j] >= thr) {
            int p = atomicAdd(&wcnt, 1);
            cvr[p] = v[j];
            cir[p] = t + 256 * j;
        }
    }
    __syncthreads();
    if (t == 0) rcnt[slot] = wcnt;
}

// ---------------- K7: out = relu(h) @ W2 + b2, h = b1 + sparse_z @ W1 (compact lists)
__global__ __launch_bounds__(256)
void k_output(const float* __restrict__ cval, const int* __restrict__ cidx,
              const int* __restrict__ rcnt,
              const float* __restrict__ W1, const float* __restrict__ b1,
              const float* __restrict__ W2, const float* __restrict__ b2,
              const int* __restrict__ perm, float* __restrict__ out) {
    __shared__ float W2s[64][68];
    __shared__ float hTs[64][34];
    __shared__ float cvS[ORB][16];
    __shared__ int   ciS[ORB][16];
    __shared__ int   cnS[ORB];

    const int t = threadIdx.x;
    const int s0 = blockIdx.x * ORB;

    if (t < ORB) cnS[t] = rcnt[s0 + t];
    __syncthreads();
    #pragma unroll
    for (int u = t; u < ORB * 16; u += 256) {
        int r = u >> 4, e = u & 15;
        int cnt = cnS[r];
        cvS[r][e] = (e < cnt) ? cval[(size_t)(s0 + r) * CD + e] : 0.f;
        ciS[r][e] = (e < cnt) ? cidx[(size_t)(s0 + r) * CD + e] : 0;
    }

    const int tm = t >> 4;
    const int tn = t & 15;
    const int iL = t & 63;
    const int rs = t >> 6;

    float acc0[4], acc1[4];
    #pragma unroll
    for (int j = 0; j < 4; ++j) { acc0[j] = 0.f; acc1[j] = 0.f; }

    for (int ch = 0; ch < 16; ++ch) {
        const int i0 = ch * 64;
        __syncthreads();
        #pragma unroll
        for (int p = 0; p < 4; ++p) {
            int kr = (t >> 4) + 16 * p;
            float4 w = *(const float4*)&W2[(size_t)(i0 + kr) * PD + (t & 15) * 4];
            *(float4*)&W2s[kr][(t & 15) * 4] = w;
        }
        float bv = b1[i0 + iL];
        #pragma unroll
        for (int jj = 0; jj < 8; ++jj) {
            int r = rs * 8 + jj;
            int cnt = cnS[r];
            float acc = bv;
            float wv[16];
            #pragma unroll
            for (int e = 0; e < 16; ++e)
                wv[e] = W1[(size_t)ciS[r][e] * CD + i0 + iL];
            #pragma unroll
            for (int e = 0; e < 16; ++e)
                acc = fmaf(cvS[r][e], wv[e], acc);
            if (cnt > 16) {
                const float* cvr = cval + (size_t)(s0 + r) * CD;
                const int* cir = cidx + (size_t)(s0 + r) * CD;
                for (int e = 16; e < cnt; ++e)
                    acc = fmaf(cvr[e], W1[(size_t)cir[e] * CD + i0 + iL], acc);
            }
            hTs[iL][r] = fmaxf(acc, 0.f);
        }
        __syncthreads();
        #pragma unroll 8
        for (int i = 0; i < 64; ++i) {
            float2 h2 = *(const float2*)&hTs[i][2 * tm];
            float4 w4 = *(const float4*)&W2s[i][4 * tn];
            const float* wp = &w4.x;
            #pragma unroll
            for (int j = 0; j < 4; ++j) {
                acc0[j] = fmaf(h2.x, wp[j], acc0[j]);
                acc1[j] = fmaf(h2.y, wp[j], acc1[j]);
            }
        }
    }

    float4 bb = *(const float4*)&b2[4 * tn];
    const float* bp = &bb.x;
    int g0 = perm[s0 + 2 * tm];
    int g1 = perm[s0 + 2 * tm + 1];
    float4 o0, o1;
    #pragma unroll
    for (int j = 0; j < 4; ++j) { (&o0.x)[j] = acc0[j] + bp[j]; (&o1.x)[j] = acc1[j] + bp[j]; }
    *(float4*)&out[(size_t)g0 * PD + 4 * tn] = o0;
    *(float4*)&out[(size_t)g1 * PD + 4 * tn] = o1;
}

extern "C" void kernel_launch(void* const* d_in, const int* in_sizes, int n_in,
                              void* d_out, int out_size, void* d_ws, size_t ws_size,
                              hipStream_t stream) {
    const float* x     = (const float*)d_in[0];
    const float* Wq    = (const float*)d_in[1];
    const float* bq    = (const float*)d_in[2];
    const float* keys  = (const float*)d_in[3];
    const float* We    = (const float*)d_in[4];
    const float* S     = (const float*)d_in[5];
    const float* theta = (const float*)d_in[6];
    const float* W1    = (const float*)d_in[7];
    const float* b1    = (const float*)d_in[8];
    const float* W2    = (const float*)d_in[9];
    const float* b2    = (const float*)d_in[10];
    float* out = (float*)d_out;

    const size_t F = (size_t)NB * CD;  // 8.39M elements
    float* Bx = (float*)d_ws;                         // region 0: F floats
    _Float16* zAh = (_Float16*)(Bx + F);              // region 1: 2F halves
    _Float16* zAl = zAh + F;
    float* R1 = (float*)(zAl + F);                    // region 2: F floats, multi-phase
    //  phase A (pre-G2): x/We split planes
    _Float16* xh  = (_Float16*)R1;
    _Float16* xl  = xh + (size_t)NB * IND;
    _Float16* weh = xl + (size_t)NB * IND;
    _Float16* wel = weh + (size_t)KE * IND * CD;
    //  phase B (G2..G5): zB ping-pong planes
    _Float16* zBh = (_Float16*)R1;
    _Float16* zBl = zBh + F;
    //  phase C (G6..): z1 fp32
    float* z1 = R1;
    _Float16* sth = (_Float16*)(R1 + F);              // region 3: 2F halves
    _Float16* stl = sth + F;
    float* M  = (float*)(stl + F);
    float* sb = M + IND * KE;
    int* idx     = (int*)(sb + 8);
    int* perm    = idx + NB;
    int* counts  = perm + NB;
    int* offsets = counts + KE;
    int* cursors = offsets + KE;
    int* rcnt    = cursors + KE;
    // compact lists alias Bx (cval) and zAh/zAl (cidx) — both dead after G6
    float* cval = Bx;
    int*   cidx = (int*)zAh;

    hipMemsetAsync(counts, 0, 3 * KE * sizeof(int), stream);
    k_split_rows<<<(NB * IND) / 1024, 256, 0, stream>>>(x, xh, xl, NB * IND);
    {
        dim3 g(IND / 64, CD / 64, KE);
        k_tsplit<<<g, 256, 0, stream>>>(We, weh, wel, IND);
    }
    {
        dim3 g(CD / 64, CD / 64, KE);
        k_tsplit<<<g, 256, 0, stream>>>(S, sth, stl, CD);
    }
    k_precompute_M<<<16, 256, 0, stream>>>(Wq, keys, bq, M, sb);
    k_scores<<<NB / 4, 256, 0, stream>>>(x, M, sb, idx, counts);
    k_offsets<<<1, 64, 0, stream>>>(counts, offsets);
    k_perm<<<NB / 256, 256, 0, stream>>>(idx, offsets, cursors, perm);

    dim3 gg(CD / 128, NB / 128, KE);
    k_mfma<IND, 0><<<gg, 256, 0, stream>>>(xh, xl, weh, wel, theta, nullptr, Bx, zAh, zAl, nullptr, perm, counts, offsets);
    k_mfma<CD, 1><<<gg, 256, 0, stream>>>(zAh, zAl, sth, stl, theta, Bx, nullptr, zBh, zBl, nullptr, perm, counts, offsets);
    k_mfma<CD, 1><<<gg, 256, 0, stream>>>(zBh, zBl, sth, stl, theta, Bx, nullptr, zAh, zAl, nullptr, perm, counts, offsets);
    k_mfma<CD, 1><<<gg, 256, 0, stream>>>(zAh, zAl, sth, stl, theta, Bx, nullptr, zBh, zBl, nullptr, perm, counts, offsets);
    k_mfma<CD, 1><<<gg, 256, 0, stream>>>(zBh, zBl, sth, stl, theta, Bx, nullptr, zAh, zAl, nullptr, perm, counts, offsets);
    k_mfma<CD, 2><<<gg, 256, 0, stream>>>(zAh, zAl, sth, stl, theta, Bx, nullptr, nullptr, nullptr, z1, perm, counts, offsets);

    k_prune<<<NB, 256, 0, stream>>>(z1, offsets, cval, cidx, rcnt);
    k_output<<<NB / ORB, 256, 0, stream>>>(cval, cidx, rcnt, W1, b1, W2, b2, perm, out);
}

// Round 6
// 944.308 us; speedup vs baseline: 4.5185x; 1.2852x over previous
//
#include <hip/hip_runtime.h>
#include <math.h>

#define NB 8192
#define IND 512
#define QDIM 128
#define CD 1024
#define KE 8
#define PD 64
#define ORB 32  // rows per k_output block

typedef _Float16 h8 __attribute__((ext_vector_type(8)));
typedef _Float16 h4 __attribute__((ext_vector_type(4)));
typedef float fx16 __attribute__((ext_vector_type(16)));

#define GLD16(g, l) __builtin_amdgcn_global_load_lds((const __attribute__((address_space(1))) void*)(g), (__attribute__((address_space(3))) void*)(l), 16, 0, 0)

__device__ __forceinline__ float softt(float v, float th) {
    float a = fabsf(v) - th;
    return a > 0.0f ? copysignf(a, v) : 0.0f;
}

// ---------------- split helpers: v = hi + lo * 2^-11 (lo stored pre-scaled by 2048)
__device__ __forceinline__ void fsplit(float v, _Float16& hi, _Float16& lo) {
    hi = (_Float16)v;
    lo = (_Float16)((v - (float)hi) * 2048.0f);
}

// ---------------- K0: M = Wq @ keys^T / sqrt(QDIM), sb = bq @ keys^T / sqrt(QDIM)
__global__ void k_precompute_M(const float* __restrict__ Wq, const float* __restrict__ keys,
                               const float* __restrict__ bq, float* __restrict__ M,
                               float* __restrict__ sb) {
    const float RSQ = 0.088388347648318447f; // 1/sqrt(128)
    int g = blockIdx.x * 256 + threadIdx.x;  // 0..4095
    if (g < IND * KE) {
        int i = g >> 3, k = g & 7;
        float s = 0.f;
        for (int q = 0; q < QDIM; ++q) s += Wq[i * QDIM + q] * keys[k * QDIM + q];
        M[g] = s * RSQ;  // M[i*8+k]
    }
    if (blockIdx.x == 0 && threadIdx.x < KE) {
        int k = threadIdx.x;
        float s = 0.f;
        for (int q = 0; q < QDIM; ++q) s += bq[q] * keys[k * QDIM + q];
        sb[k] = s * RSQ;
    }
}

// ---------------- K1: per-row scores -> expert idx, counts (one wave per row)
__global__ __launch_bounds__(256)
void k_scores(const float* __restrict__ x, const float* __restrict__ M,
              const float* __restrict__ sb, int* __restrict__ idx, int* __restrict__ counts) {
    __shared__ float Ms[KE][IND];
    __shared__ float sbs[KE];
    int t = threadIdx.x;
    #pragma unroll
    for (int j = 0; j < 16; ++j) {
        int e = j * 256 + t;
        Ms[e & 7][e >> 3] = M[e];
    }
    if (t < KE) sbs[t] = sb[t];
    __syncthreads();
    int w = t >> 6, lane = t & 63;
    int row = blockIdx.x * 4 + w;
    const float* xr = x + (size_t)row * IND;
    float sc[KE];
    #pragma unroll
    for (int k = 0; k < KE; ++k) sc[k] = 0.f;
    #pragma unroll
    for (int j = 0; j < IND / 64; ++j) {
        int ii = lane + 64 * j;
        float xv = xr[ii];
        #pragma unroll
        for (int k = 0; k < KE; ++k) sc[k] += xv * Ms[k][ii];
    }
    #pragma unroll
    for (int k = 0; k < KE; ++k) {
        #pragma unroll
        for (int off = 32; off >= 1; off >>= 1) sc[k] += __shfl_down(sc[k], off, 64);
    }
    if (lane == 0) {
        float smax = -1e30f;
        #pragma unroll
        for (int k = 0; k < KE; ++k) { sc[k] += sbs[k]; smax = fmaxf(smax, sc[k]); }
        const float LN09 = -0.105360515657826301f;  // ln(0.9)
        int e = 0;
        #pragma unroll
        for (int k = KE - 1; k >= 0; --k)
            if (sc[k] >= smax + LN09) e = k;  // smallest eligible k (sl is increasing)
        idx[row] = e;
        atomicAdd(&counts[e], 1);
    }
}

// ---------------- K2: exclusive prefix of counts
__global__ void k_offsets(const int* __restrict__ counts, int* __restrict__ offsets) {
    if (threadIdx.x == 0 && blockIdx.x == 0) {
        int acc = 0;
        for (int k = 0; k < KE; ++k) { offsets[k] = acc; acc += counts[k]; }
    }
}

// ---------------- K3: fill perm (compacted slot -> original row)
__global__ void k_perm(const int* __restrict__ idx, const int* __restrict__ offsets,
                       int* __restrict__ cursors, int* __restrict__ perm) {
    int r = blockIdx.x * 256 + threadIdx.x;
    if (r < NB) {
        int k = idx[r];
        int pos = atomicAdd(&cursors[k], 1);
        perm[offsets[k] + pos] = r;
    }
}

// ---------------- K4: elementwise split of x into hi/lo fp16 planes
__global__ __launch_bounds__(256)
void k_split_rows(const float* __restrict__ src, _Float16* __restrict__ ph,
                  _Float16* __restrict__ pl, int n) {
    int i = (blockIdx.x * 256 + threadIdx.x) * 4;
    if (i < n) {
        float4 v = *(const float4*)(src + i);
        h4 hh, ll;
        #pragma unroll
        for (int j = 0; j < 4; ++j) {
            _Float16 a, b;
            fsplit((&v.x)[j], a, b);
            hh[j] = a; ll[j] = b;
        }
        *(h4*)(ph + i) = hh;
        *(h4*)(pl + i) = ll;
    }
}

// ---------------- K5: transpose+split: src[e][K][CD] fp32 -> th/tl[e][CD][K] fp16
__global__ __launch_bounds__(256)
void k_tsplit(const float* __restrict__ src, _Float16* __restrict__ th,
              _Float16* __restrict__ tl, int K) {
    __shared__ float tile[64][65];
    int e = blockIdx.z;
    int k0 = blockIdx.x * 64;
    int n0 = blockIdx.y * 64;
    const float* s = src + (size_t)e * K * CD;
    int t = threadIdx.x;
    int tr = t >> 4;
    int tc = (t & 15) * 4;
    #pragma unroll
    for (int p = 0; p < 4; ++p) {
        int kk = tr + p * 16;
        float4 v = *(const float4*)&s[(size_t)(k0 + kk) * CD + n0 + tc];
        #pragma unroll
        for (int j = 0; j < 4; ++j) tile[kk][tc + j] = (&v.x)[j];
    }
    __syncthreads();
    int n = t >> 2;
    int kq = (t & 3) * 16;
    h8 hh0, hh1, ll0, ll1;
    #pragma unroll
    for (int j = 0; j < 8; ++j) {
        _Float16 a, b;
        fsplit(tile[kq + j][n], a, b);
        hh0[j] = a; ll0[j] = b;
        fsplit(tile[kq + 8 + j][n], a, b);
        hh1[j] = a; ll1[j] = b;
    }
    size_t ob = ((size_t)e * CD + n0 + n) * K + k0 + kq;
    *(h8*)(th + ob) = hh0;
    *(h8*)(th + ob + 8) = hh1;
    *(h8*)(tl + ob) = ll0;
    *(h8*)(tl + ob + 8) = ll1;
}

// ---------------- grouped split-fp16 MFMA GEMM, 128x128 tile, BK=32 k-values,
// double-buffered async staging (one barrier/iter) + XCD swizzle.
// A planes: [row][KDIM] fp16 hi/lo (lo pre-scaled 2048). B planes: [e][CD][KDIM] K-major.
// LDS row: 8 chunks of 16B; physical chunk = logical ^ (row&7); logical lc = kg*2+comp.
// acc1 = hi*hi; acc2 = hi*lo' + lo'*hi; result = acc1 + acc2*2^-11 (rel err 2^-22).
// MODE 0: Bx = gather(x)@We; write Bx fp32 + z hi/lo
// MODE 1: v += Bx; write z hi/lo
// MODE 2: v += Bx; write z fp32
template <int KDIM, int MODE>
__global__ __launch_bounds__(256)
void k_mfma(const _Float16* __restrict__ Ah, const _Float16* __restrict__ Al,
            const _Float16* __restrict__ Bh, const _Float16* __restrict__ Bl,
            const float* __restrict__ theta, const float* __restrict__ BxBuf,
            float* __restrict__ BxOut, _Float16* __restrict__ zh, _Float16* __restrict__ zl,
            float* __restrict__ zf,
            const int* __restrict__ perm, const int* __restrict__ counts,
            const int* __restrict__ offsets) {
    const int e = blockIdx.z;
    const int cnt = counts[e];
    // XCD swizzle: consecutive p round-robin XCDs; give each XCD an 8x8 (x,y) sub-grid.
    const int p = blockIdx.x + 8 * blockIdx.y;
    const int gx = p & 7;
    const int qq = p >> 3;
    const int bxl = qq & 7;
    const int byl = gx + 8 * (qq >> 3);
    const int m0 = byl * 128;
    if (m0 >= cnt) return;
    const int n0 = bxl * 128;
    const int off = offsets[e];
    const float th = theta[e];

    __shared__ _Float16 Asl[2][128 * 64];  // 16 KB per buffer
    __shared__ _Float16 Bsl[2][128 * 64];

    const int t = threadIdx.x;
    const int lane = t & 63;
    const int w = t >> 6;

    // staging pointers: 4 A + 4 B global_load_lds per thread per BK=32 step
    const _Float16* aptr[4];
    const _Float16* bptr[4];
    #pragma unroll
    for (int i = 0; i < 4; ++i) {
        int s = w * 4 + i;
        int r = s * 8 + (lane >> 3);
        int pc = lane & 7;
        int lc = pc ^ (r & 7);
        int comp = lc & 1;
        int kg = lc >> 1;
        int mrow = m0 + r; if (mrow > cnt - 1) mrow = cnt - 1;
        size_t grow;
        if constexpr (MODE == 0) grow = (size_t)perm[off + mrow];
        else grow = (size_t)(off + mrow);
        aptr[i] = (comp ? Al : Ah) + grow * KDIM + kg * 8;
        bptr[i] = (comp ? Bl : Bh) + ((size_t)e * CD + n0 + r) * KDIM + kg * 8;
    }

    const int wm = w >> 1, wn = w & 1;
    const int q = lane >> 5;
    const int ml = lane & 31;
    const int sw = ml & 7;

    fx16 acc1[2][2], acc2[2][2];
    #pragma unroll
    for (int mt = 0; mt < 2; ++mt)
        #pragma unroll
        for (int nt = 0; nt < 2; ++nt)
            #pragma unroll
            for (int g = 0; g < 16; ++g) { acc1[mt][nt][g] = 0.f; acc2[mt][nt][g] = 0.f; }

    auto stage = [&](int kt, int buf) {
        const int koff = kt * 32;
        #pragma unroll
        for (int i = 0; i < 4; ++i) {
            GLD16(aptr[i] + koff, &Asl[buf][(w * 4 + i) * 512]);
            GLD16(bptr[i] + koff, &Bsl[buf][(w * 4 + i) * 512]);
        }
    };

    const int NT = KDIM / 32;
    stage(0, 0);
    __syncthreads();
    for (int kt = 0; kt < NT; ++kt) {
        const int buf = kt & 1;
        if (kt + 1 < NT) stage(kt + 1, buf ^ 1);  // prefetch in flight during compute
        #pragma unroll
        for (int ks = 0; ks < 2; ++ks) {
            const int base = ks * 4 + q * 2;
            h8 ah[2], al2[2], bh2[2], bl2[2];
            #pragma unroll
            for (int mt = 0; mt < 2; ++mt) {
                int mb = (wm * 64 + mt * 32 + ml) * 64;
                ah[mt]  = *(const h8*)&Asl[buf][mb + (((base + 0) ^ sw) * 8)];
                al2[mt] = *(const h8*)&Asl[buf][mb + (((base + 1) ^ sw) * 8)];
            }
            #pragma unroll
            for (int nt = 0; nt < 2; ++nt) {
                int nb = (wn * 64 + nt * 32 + ml) * 64;
                bh2[nt] = *(const h8*)&Bsl[buf][nb + (((base + 0) ^ sw) * 8)];
                bl2[nt] = *(const h8*)&Bsl[buf][nb + (((base + 1) ^ sw) * 8)];
            }
            #pragma unroll
            for (int mt = 0; mt < 2; ++mt)
                #pragma unroll
                for (int nt = 0; nt < 2; ++nt) {
                    acc1[mt][nt] = __builtin_amdgcn_mfma_f32_32x32x16_f16(ah[mt],  bh2[nt], acc1[mt][nt], 0, 0, 0);
                    acc2[mt][nt] = __builtin_amdgcn_mfma_f32_32x32x16_f16(ah[mt],  bl2[nt], acc2[mt][nt], 0, 0, 0);
                    acc2[mt][nt] = __builtin_amdgcn_mfma_f32_32x32x16_f16(al2[mt], bh2[nt], acc2[mt][nt], 0, 0, 0);
                }
        }
        __syncthreads();  // drains prefetch after compute + protects buf reuse
    }

    // epilogue: C/D layout col=lane&31, row=(g&3)+8*(g>>2)+4*q  [m74/m101]
    const float LSC = 4.8828125e-4f;  // 2^-11
    #pragma unroll
    for (int mt = 0; mt < 2; ++mt)
        #pragma unroll
        for (int nt = 0; nt < 2; ++nt) {
            #pragma unroll
            for (int g = 0; g < 16; ++g) {
                int rl = wm * 64 + mt * 32 + (g & 3) + 8 * (g >> 2) + 4 * q;
                int mrow = m0 + rl;
                if (mrow < cnt) {
                    int col = n0 + wn * 64 + nt * 32 + ml;
                    size_t addr = (size_t)(off + mrow) * CD + col;
                    float v = acc1[mt][nt][g] + acc2[mt][nt][g] * LSC;
                    if constexpr (MODE == 0) {
                        BxOut[addr] = v;
                        float z = softt(v, th);
                        _Float16 a, b;
                        fsplit(z, a, b);
                        zh[addr] = a; zl[addr] = b;
                    } else if constexpr (MODE == 1) {
                        float z = softt(v + BxBuf[addr], th);
                        _Float16 a, b;
                        fsplit(z, a, b);
                        zh[addr] = a; zl[addr] = b;
                    } else {
                        zf[addr] = softt(v + BxBuf[addr], th);
                    }
                }
            }
        }
}

// ---------------- K6: per-row top-k threshold (bit search), emit compact (val,idx) lists
__global__ __launch_bounds__(256)
void k_prune(const float* __restrict__ z, const int* __restrict__ offsets,
             float* __restrict__ cval, int* __restrict__ cidx, int* __restrict__ rcnt) {
    __shared__ int red[4];
    __shared__ int wcnt;
    const int SL[KE] = {5, 150, 296, 441, 587, 732, 878, 1024};
    int slot = blockIdx.x;
    int k = 0;
    #pragma unroll
    for (int e = 1; e < KE; ++e)
        if (slot >= offsets[e]) k = e;
    int lvl = SL[k];
    int t = threadIdx.x;
    if (t == 0) wcnt = 0;
    const float* zr = z + (size_t)slot * CD;
    float v[4];
    unsigned ab[4];
    #pragma unroll
    for (int j = 0; j < 4; ++j) {
        v[j] = zr[t + 256 * j];
        ab[j] = __float_as_uint(fabsf(v[j]));
    }
    unsigned thr = 0;
    for (int b = 30; b >= 0; --b) {
        unsigned cand = thr | (1u << b);
        int c = 0;
        #pragma unroll
        for (int j = 0; j < 4; ++j) c += (ab[j] >= cand) ? 1 : 0;
        #pragma unroll
        for (int off = 32; off >= 1; off >>= 1) c += __shfl_down(c, off, 64);
        if ((t & 63) == 0) red[t >> 6] = c;
        __syncthreads();
        int tot = red[0] + red[1] + red[2] + red[3];
        if (tot >= lvl) thr = cand;
        __syncthreads();
    }
    float* cvr = cval + (size_t)slot * CD;
    int* cir = cidx + (size_t)slot * CD;
    #pragma unroll
    for (int j = 0; j < 4; ++j) {
        if (ab[j] >= thr) {
            int p = atomicAdd(&wcnt, 1);
            cvr[p] = v[j];
            cir[p] = t + 256 * j;
        }
    }
    __syncthreads();
    if (t == 0) rcnt[slot] = wcnt;
}

// ---------------- K7: out = relu(h) @ W2 + b2, h = b1 + sparse_z @ W1 (compact lists)
__global__ __launch_bounds__(256)
void k_output(const float* __restrict__ cval, const int* __restrict__ cidx,
              const int* __restrict__ rcnt,
              const float* __restrict__ W1, const float* __restrict__ b1,
              const float* __restrict__ W2, const float* __restrict__ b2,
              const int* __restrict__ perm, float* __restrict__ out) {
    __shared__ float W2s[64][68];
    __shared__ float hTs[64][34];
    __shared__ float cvS[ORB][16];
    __shared__ int   ciS[ORB][16];
    __shared__ int   cnS[ORB];

    const int t = threadIdx.x;
    const int s0 = blockIdx.x * ORB;

    if (t < ORB) cnS[t] = rcnt[s0 + t];
    __syncthreads();
    #pragma unroll
    for (int u = t; u < ORB * 16; u += 256) {
        int r = u >> 4, e = u & 15;
        int cnt = cnS[r];
        cvS[r][e] = (e < cnt) ? cval[(size_t)(s0 + r) * CD + e] : 0.f;
        ciS[r][e] = (e < cnt) ? cidx[(size_t)(s0 + r) * CD + e] : 0;
    }

    const int tm = t >> 4;
    const int tn = t & 15;
    const int iL = t & 63;
    const int rs = t >> 6;

    float acc0[4], acc1[4];
    #pragma unroll
    for (int j = 0; j < 4; ++j) { acc0[j] = 0.f; acc1[j] = 0.f; }

    for (int ch = 0; ch < 16; ++ch) {
        const int i0 = ch * 64;
        __syncthreads();
        #pragma unroll
        for (int p = 0; p < 4; ++p) {
            int kr = (t >> 4) + 16 * p;
            float4 w = *(const float4*)&W2[(size_t)(i0 + kr) * PD + (t & 15) * 4];
            *(float4*)&W2s[kr][(t & 15) * 4] = w;
        }
        float bv = b1[i0 + iL];
        #pragma unroll
        for (int jj = 0; jj < 8; ++jj) {
            int r = rs * 8 + jj;
            int cnt = cnS[r];
            float acc = bv;
            float wv[16];
            #pragma unroll
            for (int e = 0; e < 16; ++e)
                wv[e] = W1[(size_t)ciS[r][e] * CD + i0 + iL];
            #pragma unroll
            for (int e = 0; e < 16; ++e)
                acc = fmaf(cvS[r][e], wv[e], acc);
            if (cnt > 16) {
                const float* cvr = cval + (size_t)(s0 + r) * CD;
                const int* cir = cidx + (size_t)(s0 + r) * CD;
                for (int e = 16; e < cnt; ++e)
                    acc = fmaf(cvr[e], W1[(size_t)cir[e] * CD + i0 + iL], acc);
            }
            hTs[iL][r] = fmaxf(acc, 0.f);
        }
        __syncthreads();
        #pragma unroll 8
        for (int i = 0; i < 64; ++i) {
            float2 h2 = *(const float2*)&hTs[i][2 * tm];
            float4 w4 = *(const float4*)&W2s[i][4 * tn];
            const float* wp = &w4.x;
            #pragma unroll
            for (int j = 0; j < 4; ++j) {
                acc0[j] = fmaf(h2.x, wp[j], acc0[j]);
                acc1[j] = fmaf(h2.y, wp[j], acc1[j]);
            }
        }
    }

    float4 bb = *(const float4*)&b2[4 * tn];
    const float* bp = &bb.x;
    int g0 = perm[s0 + 2 * tm];
    int g1 = perm[s0 + 2 * tm + 1];
    float4 o0, o1;
    #pragma unroll
    for (int j = 0; j < 4; ++j) { (&o0.x)[j] = acc0[j] + bp[j]; (&o1.x)[j] = acc1[j] + bp[j]; }
    *(float4*)&out[(size_t)g0 * PD + 4 * tn] = o0;
    *(float4*)&out[(size_t)g1 * PD + 4 * tn] = o1;
}

extern "C" void kernel_launch(void* const* d_in, const int* in_sizes, int n_in,
                              void* d_out, int out_size, void* d_ws, size_t ws_size,
                              hipStream_t stream) {
    const float* x     = (const float*)d_in[0];
    const float* Wq    = (const float*)d_in[1];
    const float* bq    = (const float*)d_in[2];
    const float* keys  = (const float*)d_in[3];
    const float* We    = (const float*)d_in[4];
    const float* S     = (const float*)d_in[5];
    const float* theta = (const float*)d_in[6];
    const float* W1    = (const float*)d_in[7];
    const float* b1    = (const float*)d_in[8];
    const float* W2    = (const float*)d_in[9];
    const float* b2    = (const float*)d_in[10];
    float* out = (float*)d_out;

    const size_t F = (size_t)NB * CD;  // 8.39M elements
    float* Bx = (float*)d_ws;                         // region 0: F floats
    _Float16* zAh = (_Float16*)(Bx + F);              // region 1: 2F halves
    _Float16* zAl = zAh + F;
    float* R1 = (float*)(zAl + F);                    // region 2: F floats, multi-phase
    //  phase A (pre-G2): x/We split planes
    _Float16* xh  = (_Float16*)R1;
    _Float16* xl  = xh + (size_t)NB * IND;
    _Float16* weh = xl + (size_t)NB * IND;
    _Float16* wel = weh + (size_t)KE * IND * CD;
    //  phase B (G2..G5): zB ping-pong planes
    _Float16* zBh = (_Float16*)R1;
    _Float16* zBl = zBh + F;
    //  phase C (G6..): z1 fp32
    float* z1 = R1;
    _Float16* sth = (_Float16*)(R1 + F);              // region 3: 2F halves
    _Float16* stl = sth + F;
    float* M  = (float*)(stl + F);
    float* sb = M + IND * KE;
    int* idx     = (int*)(sb + 8);
    int* perm    = idx + NB;
    int* counts  = perm + NB;
    int* offsets = counts + KE;
    int* cursors = offsets + KE;
    int* rcnt    = cursors + KE;
    // compact lists alias Bx (cval) and zAh (cidx) — both dead after G6
    float* cval = Bx;
    int*   cidx = (int*)zAh;

    hipMemsetAsync(counts, 0, 3 * KE * sizeof(int), stream);
    k_split_rows<<<(NB * IND) / 1024, 256, 0, stream>>>(x, xh, xl, NB * IND);
    {
        dim3 g(IND / 64, CD / 64, KE);
        k_tsplit<<<g, 256, 0, stream>>>(We, weh, wel, IND);
    }
    {
        dim3 g(CD / 64, CD / 64, KE);
        k_tsplit<<<g, 256, 0, stream>>>(S, sth, stl, CD);
    }
    k_precompute_M<<<16, 256, 0, stream>>>(Wq, keys, bq, M, sb);
    k_scores<<<NB / 4, 256, 0, stream>>>(x, M, sb, idx, counts);
    k_offsets<<<1, 64, 0, stream>>>(counts, offsets);
    k_perm<<<NB / 256, 256, 0, stream>>>(idx, offsets, cursors, perm);

    dim3 gg(CD / 128, NB / 128, KE);
    k_mfma<IND, 0><<<gg, 256, 0, stream>>>(xh, xl, weh, wel, theta, nullptr, Bx, zAh, zAl, nullptr, perm, counts, offsets);
    k_mfma<CD, 1><<<gg, 256, 0, stream>>>(zAh, zAl, sth, stl, theta, Bx, nullptr, zBh, zBl, nullptr, perm, counts, offsets);
    k_mfma<CD, 1><<<gg, 256, 0, stream>>>(zBh, zBl, sth, stl, theta, Bx, nullptr, zAh, zAl, nullptr, perm, counts, offsets);
    k_mfma<CD, 1><<<gg, 256, 0, stream>>>(zAh, zAl, sth, stl, theta, Bx, nullptr, zBh, zBl, nullptr, perm, counts, offsets);
    k_mfma<CD, 1><<<gg, 256, 0, stream>>>(zBh, zBl, sth, stl, theta, Bx, nullptr, zAh, zAl, nullptr, perm, counts, offsets);
    k_mfma<CD, 2><<<gg, 256, 0, stream>>>(zAh, zAl, sth, stl, theta, Bx, nullptr, nullptr, nullptr, z1, perm, counts, offsets);

    k_prune<<<NB, 256, 0, stream>>>(z1, offsets, cval, cidx, rcnt);
    k_output<<<NB / ORB, 256, 0, stream>>>(cval, cidx, rcnt, W1, b1, W2, b2, perm, out);
}